// Round 1
// baseline (1434.460 us; speedup 1.0000x reference)
//
#include <hip/hip_runtime.h>
#include <cstdint>
#include <cstddef>

// Problem dims
static constexpr int Mrows = 4096;   // B*N = 8*512
static constexpr int K1 = 4608;      // D_IN
static constexpr int N1 = 4608;      // D_HID
static constexpr int N2 = 1152;      // D_OUT

typedef float  f32x4  __attribute__((ext_vector_type(4)));
typedef __bf16 bf16x8 __attribute__((ext_vector_type(8)));

__device__ __forceinline__ unsigned short f2bf(float f) {
  unsigned int u = __float_as_uint(f);
  u += 0x7fffu + ((u >> 16) & 1u);           // RNE
  return (unsigned short)(u >> 16);
}
__device__ __forceinline__ float bf2f(unsigned short h) {
  return __uint_as_float(((unsigned int)h) << 16);
}
__device__ __forceinline__ float cleanf(float s) {
  if (__builtin_isnan(s)) return 1e-5f;
  if (__builtin_isinf(s)) return 1.0f;
  return s;
}

// ---------------------------------------------------------------------------
// prep_in: f32 -> bf16 conversion of mu_in/sigma_in + row sums of mu^2, sigma
// one block per row (4608 cols)
// ---------------------------------------------------------------------------
__global__ __launch_bounds__(256) void prep_in(
    const float* __restrict__ mu, const float* __restrict__ sg,
    unsigned short* __restrict__ A1, unsigned short* __restrict__ As,
    float* __restrict__ rmu2, float* __restrict__ rsg)
{
  const int row = blockIdx.x;
  const int tid = threadIdx.x;
  const float4* mup = (const float4*)(mu + (size_t)row * K1);
  const float4* sgp = (const float4*)(sg + (size_t)row * K1);
  ushort4* a1p = (ushort4*)(A1 + (size_t)row * K1);
  ushort4* asp = (ushort4*)(As + (size_t)row * K1);
  float smu = 0.f, ssg = 0.f;
  for (int j = tid; j < K1 / 4; j += 256) {
    float4 m4 = mup[j];
    float4 s4 = sgp[j];
    smu += m4.x*m4.x + m4.y*m4.y + m4.z*m4.z + m4.w*m4.w;
    ssg += s4.x + s4.y + s4.z + s4.w;
    a1p[j] = make_ushort4(f2bf(m4.x), f2bf(m4.y), f2bf(m4.z), f2bf(m4.w));
    asp[j] = make_ushort4(f2bf(s4.x), f2bf(s4.y), f2bf(s4.z), f2bf(s4.w));
  }
  __shared__ float red[2][4];
  for (int off = 32; off; off >>= 1) {
    smu += __shfl_down(smu, off);
    ssg += __shfl_down(ssg, off);
  }
  const int lane = tid & 63, wv = tid >> 6;
  if (!lane) { red[0][wv] = smu; red[1][wv] = ssg; }
  __syncthreads();
  if (tid == 0) {
    rmu2[row] = red[0][0] + red[0][1] + red[0][2] + red[0][3];
    rsg[row]  = red[1][0] + red[1][1] + red[1][2] + red[1][3];
  }
}

// ---------------------------------------------------------------------------
// prep_w: transpose+convert w[K,N] f32 -> Bt[N,K] bf16 and Bsq[N,K]=bf16(w^2),
// and accumulate total sum of w^2 (for KL) via one atomic per block.
// grid (K/32, N/32), 256 threads (32x8)
// ---------------------------------------------------------------------------
__global__ __launch_bounds__(256) void prep_w(
    const float* __restrict__ w, unsigned short* __restrict__ Bt,
    unsigned short* __restrict__ Bsq, float* __restrict__ sumsq, int sumidx,
    int K, int N)
{
  __shared__ float t[32][33];
  const int kt = blockIdx.x * 32;
  const int nt = blockIdx.y * 32;
  const int tx = threadIdx.x & 31;
  const int ty = threadIdx.x >> 5;   // 0..7
  float loc = 0.f;
#pragma unroll
  for (int i = 0; i < 32; i += 8) {
    float v = w[(size_t)(kt + ty + i) * N + (nt + tx)];
    t[ty + i][tx] = v;
    loc += v * v;
  }
  __syncthreads();
#pragma unroll
  for (int i = 0; i < 32; i += 8) {
    float v = t[tx][ty + i];                  // = w[kt+tx][nt+ty+i]
    size_t o = (size_t)(nt + ty + i) * K + (kt + tx);
    Bt[o]  = f2bf(v);
    Bsq[o] = f2bf(v * v);
  }
  // block-reduce loc, one atomic
  __shared__ float red[4];
  for (int off = 32; off; off >>= 1) loc += __shfl_down(loc, off);
  const int lane = threadIdx.x & 63, wv = threadIdx.x >> 6;
  if (!lane) red[wv] = loc;
  __syncthreads();
  if (threadIdx.x == 0)
    atomicAdd(&sumsq[sumidx], red[0] + red[1] + red[2] + red[3]);
}

// ---------------------------------------------------------------------------
// kl_prep: softplus vectors ws1/ws2, KL scalar (written to d_out tail)
// single block of 256
// ---------------------------------------------------------------------------
__global__ __launch_bounds__(256) void kl_prep(
    const float* __restrict__ wsig1, const float* __restrict__ wsig2,
    const float* __restrict__ sumsq, float* __restrict__ ws1,
    float* __restrict__ ws2, float* __restrict__ outkl)
{
  const int tid = threadIdx.x;
  float s1 = 0.f, l1 = 0.f, s2 = 0.f, l2 = 0.f;
  for (int j = tid; j < N1; j += 256) {
    float x = wsig1[j];
    float sp = (x > 20.f) ? x : log1pf(expf(x));
    ws1[j] = sp; s1 += sp; l1 += logf(sp);
  }
  for (int j = tid; j < N2; j += 256) {
    float x = wsig2[j];
    float sp = (x > 20.f) ? x : log1pf(expf(x));
    ws2[j] = sp; s2 += sp; l2 += logf(sp);
  }
  __shared__ float red[4][4];
  for (int off = 32; off; off >>= 1) {
    s1 += __shfl_down(s1, off); l1 += __shfl_down(l1, off);
    s2 += __shfl_down(s2, off); l2 += __shfl_down(l2, off);
  }
  const int lane = tid & 63, wv = tid >> 6;
  if (!lane) { red[0][wv] = s1; red[1][wv] = l1; red[2][wv] = s2; red[3][wv] = l2; }
  __syncthreads();
  if (tid == 0) {
    float S1v = red[0][0] + red[0][1] + red[0][2] + red[0][3];
    float L1v = red[1][0] + red[1][1] + red[1][2] + red[1][3];
    float S2v = red[2][0] + red[2][1] + red[2][2] + red[2][3];
    float L2v = red[3][0] + red[3][1] + red[3][2] + red[3][3];
    const float d = 4608.f;   // w_mu.shape[0] for BOTH layers
    float kl1 = 0.5f * (d * (S1v / (float)N1) + sumsq[0] / (float)N1 - d - d * (L1v / (float)N1));
    float kl2 = 0.5f * (d * (S2v / (float)N2) + sumsq[1] / (float)N2 - d - d * (L2v / (float)N2));
    outkl[0] = kl1 + kl2;
  }
}

// ---------------------------------------------------------------------------
// gemm_bt: C[M,N] = A[M,K] * Bt[N,K]^T   (bf16 in, f32 accum, CT out)
// 128x128 tile, 256 threads = 4 waves (2x2 of 64x64), BK=32,
// 16x16x32 bf16 MFMA, global_load_lds width-16 staging, XOR chunk swizzle.
// M,N multiples of 128; K multiple of 32.
// ---------------------------------------------------------------------------
#define GLD16(gp, lp) __builtin_amdgcn_global_load_lds( \
    (__attribute__((address_space(1))) void*)(unsigned short*)(gp), \
    (__attribute__((address_space(3))) void*)(lp), 16, 0, 0)

__device__ __forceinline__ void storeC(float v, float* p) { *p = v; }
__device__ __forceinline__ void storeC(float v, unsigned short* p) { *p = f2bf(v); }

template <typename CT>
__global__ __launch_bounds__(256) void gemm_bt(
    const unsigned short* __restrict__ A, const unsigned short* __restrict__ Bt,
    CT* __restrict__ C, int M, int N, int K)
{
  __shared__ unsigned short lA[128 * 32];
  __shared__ unsigned short lB[128 * 32];
  const int tid = threadIdx.x;
  const int lane = tid & 63;
  const int wave = tid >> 6;
  const int m0 = blockIdx.y * 128;
  const int n0 = blockIdx.x * 128;
  const int wm = (wave & 1) * 64;
  const int wn = (wave >> 1) * 64;

  f32x4 acc[4][4];
#pragma unroll
  for (int i = 0; i < 4; i++)
#pragma unroll
    for (int j = 0; j < 4; j++) acc[i][j] = (f32x4){0.f, 0.f, 0.f, 0.f};

  // staging: chunk c -> LDS slot c (forced linear); global chunk = (c&3) ^ swz(row)
  const int c0 = tid, c1 = tid + 256;
  const int r0s = c0 >> 2, k0s = (c0 & 3) ^ ((r0s >> 1) & 3);
  const int r1s = c1 >> 2, k1s = (c1 & 3) ^ ((r1s >> 1) & 3);
  const unsigned short* gA0 = A + (size_t)(m0 + r0s) * K + k0s * 8;
  const unsigned short* gA1 = A + (size_t)(m0 + r1s) * K + k1s * 8;
  const unsigned short* gB0 = Bt + (size_t)(n0 + r0s) * K + k0s * 8;
  const unsigned short* gB1 = Bt + (size_t)(n0 + r1s) * K + k1s * 8;
  unsigned short* lA0 = &lA[c0 * 8];
  unsigned short* lA1 = &lA[c1 * 8];
  unsigned short* lB0 = &lB[c0 * 8];
  unsigned short* lB1 = &lB[c1 * 8];

  // fragment read offsets (elements) — match the store-side swizzle
  const int fm = lane & 15;
  const int kq = lane >> 4;          // which 8-wide k chunk
  int aoff[4], boff[4];
#pragma unroll
  for (int i = 0; i < 4; i++) {
    int ra = wm + i * 16 + fm;
    aoff[i] = ra * 32 + ((kq ^ ((ra >> 1) & 3)) * 8);
    int rb = wn + i * 16 + fm;
    boff[i] = rb * 32 + ((kq ^ ((rb >> 1) & 3)) * 8);
  }

  const int ksteps = K >> 5;
  for (int kt = 0; kt < ksteps; kt++) {
    __syncthreads();                       // protect LDS from prior readers
    GLD16(gA0, lA0); GLD16(gA1, lA1);
    GLD16(gB0, lB0); GLD16(gB1, lB1);
    gA0 += 32; gA1 += 32; gB0 += 32; gB1 += 32;
    __syncthreads();                       // drain staging (vmcnt(0) before barrier)
    bf16x8 af[4], bfr[4];
#pragma unroll
    for (int i = 0; i < 4; i++) af[i] = *(const bf16x8*)&lA[aoff[i]];
#pragma unroll
    for (int i = 0; i < 4; i++) bfr[i] = *(const bf16x8*)&lB[boff[i]];
#pragma unroll
    for (int i = 0; i < 4; i++)
#pragma unroll
      for (int j = 0; j < 4; j++)
        acc[i][j] = __builtin_amdgcn_mfma_f32_16x16x32_bf16(af[i], bfr[j], acc[i][j], 0, 0, 0);
  }

  // epilogue: C/D layout col=lane&15, row=(lane>>4)*4+reg
  const int rr = (lane >> 4) * 4;
  const int cc = lane & 15;
#pragma unroll
  for (int i = 0; i < 4; i++) {
    const int grow = m0 + wm + i * 16 + rr;
#pragma unroll
    for (int j = 0; j < 4; j++) {
      const int gcol = n0 + wn + j * 16 + cc;
      CT* cp = C + (size_t)grow * N + gcol;
#pragma unroll
      for (int r = 0; r < 4; r++) storeC(acc[i][j][r], cp + (size_t)r * N);
    }
  }
}

// ---------------------------------------------------------------------------
// mid: layer-1 epilogue. sig1 = clean(S1 + (rmu2+rsg)*ws1[col]); GELU moments;
// dropout; emit bf16 layer-2 activations + row sums of mu3^2 and sig3.
// one block per row.
// ---------------------------------------------------------------------------
__global__ __launch_bounds__(256) void mid_kernel(
    const unsigned short* __restrict__ mu1, const unsigned short* __restrict__ S1,
    const int* __restrict__ mask1, const float* __restrict__ ws1,
    const float* __restrict__ rmu2, const float* __restrict__ rsg,
    unsigned short* __restrict__ A2, unsigned short* __restrict__ As2,
    float* __restrict__ r2mu, float* __restrict__ r2sg)
{
  const int row = blockIdx.x;
  const int tid = threadIdx.x;
  const float rterm = rmu2[row] + rsg[row];
  const ushort4* mup = (const ushort4*)(mu1 + (size_t)row * N1);
  const ushort4* s1p = (const ushort4*)(S1 + (size_t)row * N1);
  const int4* mkp = (const int4*)(mask1 + (size_t)row * N1);
  const float4* wsp = (const float4*)ws1;
  ushort4* a2p = (ushort4*)(A2 + (size_t)row * N1);
  ushort4* as2p = (ushort4*)(As2 + (size_t)row * N1);
  float smu = 0.f, ssg = 0.f;
  for (int j = tid; j < N1 / 4; j += 256) {
    ushort4 m4 = mup[j]; ushort4 s4 = s1p[j]; int4 k4 = mkp[j]; float4 w4 = wsp[j];
    float xv[4] = {bf2f(m4.x), bf2f(m4.y), bf2f(m4.z), bf2f(m4.w)};
    float Sv[4] = {bf2f(s4.x), bf2f(s4.y), bf2f(s4.z), bf2f(s4.w)};
    float wv[4] = {w4.x, w4.y, w4.z, w4.w};
    int   kv[4] = {k4.x, k4.y, k4.z, k4.w};
    unsigned short oa[4], os[4];
#pragma unroll
    for (int t = 0; t < 4; t++) {
      float sig1 = cleanf(Sv[t] + rterm * wv[t]);
      float x = xv[t];
      float cdf = 0.5f * (1.f + erff(x * 0.70710678118654752f));
      float pdf = expf(-0.5f * x * x) * 0.3989422804014327f;
      float g = cdf + x * pdf;
      float mu2v = x * cdf;
      float sig2 = g * g * sig1;
      float mm = (float)kv[t];
      float mu3 = mu2v * mm * (1.f / 0.9f);
      float sig3 = cleanf(sig2 * mm * (1.f / 4608.f));
      smu += mu3 * mu3;
      ssg += sig3;
      oa[t] = f2bf(mu3);
      os[t] = f2bf(sig3);
    }
    a2p[j] = make_ushort4(oa[0], oa[1], oa[2], oa[3]);
    as2p[j] = make_ushort4(os[0], os[1], os[2], os[3]);
  }
  __shared__ float red[2][4];
  for (int off = 32; off; off >>= 1) {
    smu += __shfl_down(smu, off);
    ssg += __shfl_down(ssg, off);
  }
  const int lane = tid & 63, wv2 = tid >> 6;
  if (!lane) { red[0][wv2] = smu; red[1][wv2] = ssg; }
  __syncthreads();
  if (tid == 0) {
    r2mu[row] = red[0][0] + red[0][1] + red[0][2] + red[0][3];
    r2sg[row] = red[1][0] + red[1][1] + red[1][2] + red[1][3];
  }
}

// ---------------------------------------------------------------------------
// final: layer-2 epilogue + dropout2 + write outputs
// one block per row (1152 cols)
// ---------------------------------------------------------------------------
__global__ __launch_bounds__(256) void final_kernel(
    const float* __restrict__ mu4, const float* __restrict__ S1b,
    const int* __restrict__ mask2, const float* __restrict__ ws2,
    const float* __restrict__ r2mu, const float* __restrict__ r2sg,
    float* __restrict__ out_mu, float* __restrict__ out_sig)
{
  const int row = blockIdx.x;
  const int tid = threadIdx.x;
  const float rterm = r2mu[row] + r2sg[row];
  const float4* mup = (const float4*)(mu4 + (size_t)row * N2);
  const float4* sbp = (const float4*)(S1b + (size_t)row * N2);
  const int4* mkp = (const int4*)(mask2 + (size_t)row * N2);
  const float4* wsp = (const float4*)ws2;
  float4* omp = (float4*)(out_mu + (size_t)row * N2);
  float4* osp = (float4*)(out_sig + (size_t)row * N2);
  for (int j = tid; j < N2 / 4; j += 256) {
    float4 m4 = mup[j]; float4 s4 = sbp[j]; int4 k4 = mkp[j]; float4 w4 = wsp[j];
    float mo[4], so[4];
    float mv[4] = {m4.x, m4.y, m4.z, m4.w};
    float sv[4] = {s4.x, s4.y, s4.z, s4.w};
    float wv[4] = {w4.x, w4.y, w4.z, w4.w};
    int   kv[4] = {k4.x, k4.y, k4.z, k4.w};
#pragma unroll
    for (int t = 0; t < 4; t++) {
      float sig4 = cleanf(sv[t] + rterm * wv[t]);
      float mm = (float)kv[t];
      float mu5 = mv[t] * mm * (1.f / 0.9f);
      float sig5 = cleanf(sig4 * mm * (1.f / 1152.f));
      mo[t] = mu5;
      so[t] = cleanf(sig5);
    }
    omp[j] = make_float4(mo[0], mo[1], mo[2], mo[3]);
    osp[j] = make_float4(so[0], so[1], so[2], so[3]);
  }
}

// ---------------------------------------------------------------------------
extern "C" void kernel_launch(void* const* d_in, const int* in_sizes, int n_in,
                              void* d_out, int out_size, void* d_ws, size_t ws_size,
                              hipStream_t stream)
{
  const float* mu_in = (const float*)d_in[0];
  const float* sg_in = (const float*)d_in[1];
  const int* mask1 = (const int*)d_in[2];
  const int* mask2 = (const int*)d_in[3];
  const float* w_mu1 = (const float*)d_in[4];
  const float* wsig1 = (const float*)d_in[5];
  const float* w_mu2 = (const float*)d_in[6];
  const float* wsig2 = (const float*)d_in[7];
  float* out = (float*)d_out;

  char* ws = (char*)d_ws;
  size_t cur = 0;
  auto alloc = [&](size_t bytes) -> void* {
    void* p = ws + cur;
    cur += (bytes + 255) & ~(size_t)255;
    return p;
  };
  unsigned short* A1   = (unsigned short*)alloc((size_t)Mrows * K1 * 2);  // also A2
  unsigned short* As   = (unsigned short*)alloc((size_t)Mrows * K1 * 2);  // also As2
  unsigned short* B1t  = (unsigned short*)alloc((size_t)N1 * K1 * 2);     // also mu4 (f32) after GEMM1
  unsigned short* B1q  = (unsigned short*)alloc((size_t)N1 * K1 * 2);     // also S1b (f32) after GEMM1
  unsigned short* B2t  = (unsigned short*)alloc((size_t)N2 * K1 * 2);
  unsigned short* B2q  = (unsigned short*)alloc((size_t)N2 * K1 * 2);
  unsigned short* mu1b = (unsigned short*)alloc((size_t)Mrows * N1 * 2);
  unsigned short* S1b16= (unsigned short*)alloc((size_t)Mrows * N1 * 2);
  float* rmu2 = (float*)alloc(Mrows * 4);
  float* rsg  = (float*)alloc(Mrows * 4);
  float* r2mu = (float*)alloc(Mrows * 4);
  float* r2sg = (float*)alloc(Mrows * 4);
  float* ws1  = (float*)alloc(N1 * 4);
  float* ws2  = (float*)alloc(N2 * 4);
  float* sumsq= (float*)alloc(2 * 4);

  float* mu4  = (float*)B1t;   // reuse (B1t dead after GEMM1_mu)
  float* S1b  = (float*)B1q;   // reuse (B1q dead after GEMM1_sig)

  hipMemsetAsync(sumsq, 0, 2 * sizeof(float), stream);

  prep_in<<<Mrows, 256, 0, stream>>>(mu_in, sg_in, A1, As, rmu2, rsg);
  prep_w<<<dim3(K1 / 32, N1 / 32), 256, 0, stream>>>(w_mu1, B1t, B1q, sumsq, 0, K1, N1);
  prep_w<<<dim3(K1 / 32, N2 / 32), 256, 0, stream>>>(w_mu2, B2t, B2q, sumsq, 1, K1, N2);
  kl_prep<<<1, 256, 0, stream>>>(wsig1, wsig2, sumsq, ws1, ws2, out + (size_t)2 * Mrows * N2);

  gemm_bt<unsigned short><<<dim3(N1 / 128, Mrows / 128), 256, 0, stream>>>(A1, B1t, mu1b, Mrows, N1, K1);
  gemm_bt<unsigned short><<<dim3(N1 / 128, Mrows / 128), 256, 0, stream>>>(As, B1q, S1b16, Mrows, N1, K1);

  mid_kernel<<<Mrows, 256, 0, stream>>>(mu1b, S1b16, mask1, ws1, rmu2, rsg, A1, As, r2mu, r2sg);

  gemm_bt<float><<<dim3(N2 / 128, Mrows / 128), 256, 0, stream>>>(A1, B2t, mu4, Mrows, N2, K1);
  gemm_bt<float><<<dim3(N2 / 128, Mrows / 128), 256, 0, stream>>>(As, B2q, S1b, Mrows, N2, K1);

  final_kernel<<<Mrows, 256, 0, stream>>>(mu4, S1b, mask2, ws2, r2mu, r2sg,
                                          out, out + (size_t)Mrows * N2);
  (void)in_sizes; (void)n_in; (void)out_size; (void)ws_size;
}

// Round 2
// 1415.799 us; speedup vs baseline: 1.0132x; 1.0132x over previous
//
#include <hip/hip_runtime.h>
#include <cstdint>
#include <cstddef>

// Problem dims
static constexpr int Mrows = 4096;   // B*N = 8*512
static constexpr int K1 = 4608;      // D_IN
static constexpr int N1 = 4608;      // D_HID
static constexpr int N2 = 1152;      // D_OUT
static constexpr int SPLITK = 4;     // layer-2 K split

typedef float  f32x4  __attribute__((ext_vector_type(4)));
typedef __bf16 bf16x8 __attribute__((ext_vector_type(8)));

__device__ __forceinline__ unsigned short f2bf(float f) {
  unsigned int u = __float_as_uint(f);
  u += 0x7fffu + ((u >> 16) & 1u);           // RNE
  return (unsigned short)(u >> 16);
}
__device__ __forceinline__ float bf2f(unsigned short h) {
  return __uint_as_float(((unsigned int)h) << 16);
}
__device__ __forceinline__ float cleanf(float s) {
  if (__builtin_isnan(s)) return 1e-5f;
  if (__builtin_isinf(s)) return 1.0f;
  return s;
}

// ---------------------------------------------------------------------------
// prep_in: f32 -> bf16 conversion of mu_in/sigma_in + row sums of mu^2, sigma
// ---------------------------------------------------------------------------
__global__ __launch_bounds__(256) void prep_in(
    const float* __restrict__ mu, const float* __restrict__ sg,
    unsigned short* __restrict__ A1, unsigned short* __restrict__ As,
    float* __restrict__ rmu2, float* __restrict__ rsg)
{
  const int row = blockIdx.x;
  const int tid = threadIdx.x;
  const float4* mup = (const float4*)(mu + (size_t)row * K1);
  const float4* sgp = (const float4*)(sg + (size_t)row * K1);
  ushort4* a1p = (ushort4*)(A1 + (size_t)row * K1);
  ushort4* asp = (ushort4*)(As + (size_t)row * K1);
  float smu = 0.f, ssg = 0.f;
  for (int j = tid; j < K1 / 4; j += 256) {
    float4 m4 = mup[j];
    float4 s4 = sgp[j];
    smu += m4.x*m4.x + m4.y*m4.y + m4.z*m4.z + m4.w*m4.w;
    ssg += s4.x + s4.y + s4.z + s4.w;
    a1p[j] = make_ushort4(f2bf(m4.x), f2bf(m4.y), f2bf(m4.z), f2bf(m4.w));
    asp[j] = make_ushort4(f2bf(s4.x), f2bf(s4.y), f2bf(s4.z), f2bf(s4.w));
  }
  __shared__ float red[2][4];
  for (int off = 32; off; off >>= 1) {
    smu += __shfl_down(smu, off);
    ssg += __shfl_down(ssg, off);
  }
  const int lane = tid & 63, wv = tid >> 6;
  if (!lane) { red[0][wv] = smu; red[1][wv] = ssg; }
  __syncthreads();
  if (tid == 0) {
    rmu2[row] = red[0][0] + red[0][1] + red[0][2] + red[0][3];
    rsg[row]  = red[1][0] + red[1][1] + red[1][2] + red[1][3];
  }
}

// ---------------------------------------------------------------------------
// prep_w: transpose+convert w[K,N] f32 -> Bt[N,K] bf16 and Bsq[N,K]=bf16(w^2)
// + sum of w^2 (KL) via one atomic per block.
// ---------------------------------------------------------------------------
__global__ __launch_bounds__(256) void prep_w(
    const float* __restrict__ w, unsigned short* __restrict__ Bt,
    unsigned short* __restrict__ Bsq, float* __restrict__ sumsq, int sumidx,
    int K, int N)
{
  __shared__ float t[32][33];
  const int kt = blockIdx.x * 32;
  const int nt = blockIdx.y * 32;
  const int tx = threadIdx.x & 31;
  const int ty = threadIdx.x >> 5;   // 0..7
  float loc = 0.f;
#pragma unroll
  for (int i = 0; i < 32; i += 8) {
    float v = w[(size_t)(kt + ty + i) * N + (nt + tx)];
    t[ty + i][tx] = v;
    loc += v * v;
  }
  __syncthreads();
#pragma unroll
  for (int i = 0; i < 32; i += 8) {
    float v = t[tx][ty + i];                  // = w[kt+tx][nt+ty+i]
    size_t o = (size_t)(nt + ty + i) * K + (kt + tx);
    Bt[o]  = f2bf(v);
    Bsq[o] = f2bf(v * v);
  }
  __shared__ float red[4];
  for (int off = 32; off; off >>= 1) loc += __shfl_down(loc, off);
  const int lane = threadIdx.x & 63, wv = threadIdx.x >> 6;
  if (!lane) red[wv] = loc;
  __syncthreads();
  if (threadIdx.x == 0)
    atomicAdd(&sumsq[sumidx], red[0] + red[1] + red[2] + red[3]);
}

// ---------------------------------------------------------------------------
// kl_prep: softplus vectors ws1/ws2, KL scalar
// ---------------------------------------------------------------------------
__global__ __launch_bounds__(256) void kl_prep(
    const float* __restrict__ wsig1, const float* __restrict__ wsig2,
    const float* __restrict__ sumsq, float* __restrict__ ws1,
    float* __restrict__ ws2, float* __restrict__ outkl)
{
  const int tid = threadIdx.x;
  float s1 = 0.f, l1 = 0.f, s2 = 0.f, l2 = 0.f;
  for (int j = tid; j < N1; j += 256) {
    float x = wsig1[j];
    float sp = (x > 20.f) ? x : log1pf(expf(x));
    ws1[j] = sp; s1 += sp; l1 += logf(sp);
  }
  for (int j = tid; j < N2; j += 256) {
    float x = wsig2[j];
    float sp = (x > 20.f) ? x : log1pf(expf(x));
    ws2[j] = sp; s2 += sp; l2 += logf(sp);
  }
  __shared__ float red[4][4];
  for (int off = 32; off; off >>= 1) {
    s1 += __shfl_down(s1, off); l1 += __shfl_down(l1, off);
    s2 += __shfl_down(s2, off); l2 += __shfl_down(l2, off);
  }
  const int lane = tid & 63, wv = tid >> 6;
  if (!lane) { red[0][wv] = s1; red[1][wv] = l1; red[2][wv] = s2; red[3][wv] = l2; }
  __syncthreads();
  if (tid == 0) {
    float S1v = red[0][0] + red[0][1] + red[0][2] + red[0][3];
    float L1v = red[1][0] + red[1][1] + red[1][2] + red[1][3];
    float S2v = red[2][0] + red[2][1] + red[2][2] + red[2][3];
    float L2v = red[3][0] + red[3][1] + red[3][2] + red[3][3];
    const float d = 4608.f;   // w_mu.shape[0] for BOTH layers
    float kl1 = 0.5f * (d * (S1v / (float)N1) + sumsq[0] / (float)N1 - d - d * (L1v / (float)N1));
    float kl2 = 0.5f * (d * (S2v / (float)N2) + sumsq[1] / (float)N2 - d - d * (L2v / (float)N2));
    outkl[0] = kl1 + kl2;
  }
}

// ---------------------------------------------------------------------------
// gemm_bt: C[M,N] (slice z) = A[M, kbase:kbase+Klen] * Bt[N, ...]^T
// bf16 in, f32 accum, CT out. 128x128 tile, 4 waves, BK=32, 16x16x32 MFMA,
// global_load_lds width-16, XOR chunk swizzle (0 bank conflicts measured).
// 8x8 supertile blockIdx swizzle for L2 locality. gridDim.y % 8 == 0.
// ---------------------------------------------------------------------------
#define GLD16(gp, lp) __builtin_amdgcn_global_load_lds( \
    (__attribute__((address_space(1))) void*)(unsigned short*)(gp), \
    (__attribute__((address_space(3))) void*)(lp), 16, 0, 0)

__device__ __forceinline__ void storeC(float v, float* p) { *p = v; }
__device__ __forceinline__ void storeC(float v, unsigned short* p) { *p = f2bf(v); }

template <typename CT>
__global__ __launch_bounds__(256) void gemm_bt(
    const unsigned short* __restrict__ A, const unsigned short* __restrict__ Bt,
    CT* __restrict__ C, int M, int N, int Kstride, int Klen)
{
  __shared__ unsigned short lA[128 * 32];
  __shared__ unsigned short lB[128 * 32];
  const int tid = threadIdx.x;
  const int lane = tid & 63;
  const int wave = tid >> 6;

  // 8x8 supertile swizzle: concurrent blocks share a small set of A/B panels
  const int fl = blockIdx.y * gridDim.x + blockIdx.x;
  const int band = fl / (8 * gridDim.x);
  const int rem = fl % (8 * gridDim.x);
  const int by = band * 8 + (rem & 7);
  const int bx = rem >> 3;

  const int m0 = by * 128;
  const int n0 = bx * 128;
  const int wm = (wave & 1) * 64;
  const int wn = (wave >> 1) * 64;

  // split-K slice
  const int koff = blockIdx.z * Klen;
  A += koff;
  Bt += koff;
  C += (size_t)blockIdx.z * M * N;

  f32x4 acc[4][4];
#pragma unroll
  for (int i = 0; i < 4; i++)
#pragma unroll
    for (int j = 0; j < 4; j++) acc[i][j] = (f32x4){0.f, 0.f, 0.f, 0.f};

  // staging: chunk c -> LDS slot c (linear, forced); global chunk = (c&3) ^ swz(row)
  const int c0 = tid, c1 = tid + 256;
  const int r0s = c0 >> 2, k0s = (c0 & 3) ^ ((r0s >> 1) & 3);
  const int r1s = c1 >> 2, k1s = (c1 & 3) ^ ((r1s >> 1) & 3);
  const unsigned short* gA0 = A + (size_t)(m0 + r0s) * Kstride + k0s * 8;
  const unsigned short* gA1 = A + (size_t)(m0 + r1s) * Kstride + k1s * 8;
  const unsigned short* gB0 = Bt + (size_t)(n0 + r0s) * Kstride + k0s * 8;
  const unsigned short* gB1 = Bt + (size_t)(n0 + r1s) * Kstride + k1s * 8;
  unsigned short* lA0 = &lA[c0 * 8];
  unsigned short* lA1 = &lA[c1 * 8];
  unsigned short* lB0 = &lB[c0 * 8];
  unsigned short* lB1 = &lB[c1 * 8];

  // fragment read offsets (elements) — match the store-side swizzle
  const int fm = lane & 15;
  const int kq = lane >> 4;          // which 8-wide k chunk
  int aoff[4], boff[4];
#pragma unroll
  for (int i = 0; i < 4; i++) {
    int ra = wm + i * 16 + fm;
    aoff[i] = ra * 32 + ((kq ^ ((ra >> 1) & 3)) * 8);
    int rb = wn + i * 16 + fm;
    boff[i] = rb * 32 + ((kq ^ ((rb >> 1) & 3)) * 8);
  }

  const int ksteps = Klen >> 5;
  for (int kt = 0; kt < ksteps; kt++) {
    __syncthreads();                       // protect LDS from prior readers
    GLD16(gA0, lA0); GLD16(gA1, lA1);
    GLD16(gB0, lB0); GLD16(gB1, lB1);
    gA0 += 32; gA1 += 32; gB0 += 32; gB1 += 32;
    __syncthreads();                       // drain staging
    bf16x8 af[4], bfr[4];
#pragma unroll
    for (int i = 0; i < 4; i++) af[i] = *(const bf16x8*)&lA[aoff[i]];
#pragma unroll
    for (int i = 0; i < 4; i++) bfr[i] = *(const bf16x8*)&lB[boff[i]];
#pragma unroll
    for (int i = 0; i < 4; i++)
#pragma unroll
      for (int j = 0; j < 4; j++)
        acc[i][j] = __builtin_amdgcn_mfma_f32_16x16x32_bf16(af[i], bfr[j], acc[i][j], 0, 0, 0);
  }

  // epilogue: C/D layout col=lane&15, row=(lane>>4)*4+reg
  const int rr = (lane >> 4) * 4;
  const int cc = lane & 15;
#pragma unroll
  for (int i = 0; i < 4; i++) {
    const int grow = m0 + wm + i * 16 + rr;
#pragma unroll
    for (int j = 0; j < 4; j++) {
      const int gcol = n0 + wn + j * 16 + cc;
      CT* cp = C + (size_t)grow * N + gcol;
#pragma unroll
      for (int r = 0; r < 4; r++) storeC(acc[i][j][r], cp + (size_t)r * N);
    }
  }
}

// ---------------------------------------------------------------------------
// mid: layer-1 epilogue: sigma assembly, GELU moments, dropout, bf16 emit,
// row sums for layer-2 Sigma_2/Sigma_3 terms.
// ---------------------------------------------------------------------------
__global__ __launch_bounds__(256) void mid_kernel(
    const unsigned short* __restrict__ mu1, const unsigned short* __restrict__ S1,
    const int* __restrict__ mask1, const float* __restrict__ ws1,
    const float* __restrict__ rmu2, const float* __restrict__ rsg,
    unsigned short* __restrict__ A2, unsigned short* __restrict__ As2,
    float* __restrict__ r2mu, float* __restrict__ r2sg)
{
  const int row = blockIdx.x;
  const int tid = threadIdx.x;
  const float rterm = rmu2[row] + rsg[row];
  const ushort4* mup = (const ushort4*)(mu1 + (size_t)row * N1);
  const ushort4* s1p = (const ushort4*)(S1 + (size_t)row * N1);
  const int4* mkp = (const int4*)(mask1 + (size_t)row * N1);
  const float4* wsp = (const float4*)ws1;
  ushort4* a2p = (ushort4*)(A2 + (size_t)row * N1);
  ushort4* as2p = (ushort4*)(As2 + (size_t)row * N1);
  float smu = 0.f, ssg = 0.f;
  for (int j = tid; j < N1 / 4; j += 256) {
    ushort4 m4 = mup[j]; ushort4 s4 = s1p[j]; int4 k4 = mkp[j]; float4 w4 = wsp[j];
    float xv[4] = {bf2f(m4.x), bf2f(m4.y), bf2f(m4.z), bf2f(m4.w)};
    float Sv[4] = {bf2f(s4.x), bf2f(s4.y), bf2f(s4.z), bf2f(s4.w)};
    float wv[4] = {w4.x, w4.y, w4.z, w4.w};
    int   kv[4] = {k4.x, k4.y, k4.z, k4.w};
    unsigned short oa[4], os[4];
#pragma unroll
    for (int t = 0; t < 4; t++) {
      float sig1 = cleanf(Sv[t] + rterm * wv[t]);
      float x = xv[t];
      float cdf = 0.5f * (1.f + erff(x * 0.70710678118654752f));
      float pdf = expf(-0.5f * x * x) * 0.3989422804014327f;
      float g = cdf + x * pdf;
      float mu2v = x * cdf;
      float sig2 = g * g * sig1;
      float mm = (float)kv[t];
      float mu3 = mu2v * mm * (1.f / 0.9f);
      float sig3 = cleanf(sig2 * mm * (1.f / 4608.f));
      smu += mu3 * mu3;
      ssg += sig3;
      oa[t] = f2bf(mu3);
      os[t] = f2bf(sig3);
    }
    a2p[j] = make_ushort4(oa[0], oa[1], oa[2], oa[3]);
    as2p[j] = make_ushort4(os[0], os[1], os[2], os[3]);
  }
  __shared__ float red[2][4];
  for (int off = 32; off; off >>= 1) {
    smu += __shfl_down(smu, off);
    ssg += __shfl_down(ssg, off);
  }
  const int lane = tid & 63, wv2 = tid >> 6;
  if (!lane) { red[0][wv2] = smu; red[1][wv2] = ssg; }
  __syncthreads();
  if (tid == 0) {
    r2mu[row] = red[0][0] + red[0][1] + red[0][2] + red[0][3];
    r2sg[row] = red[1][0] + red[1][1] + red[1][2] + red[1][3];
  }
}

// ---------------------------------------------------------------------------
// final: split-K reduction + layer-2 epilogue + dropout2 + outputs
// ---------------------------------------------------------------------------
__global__ __launch_bounds__(256) void final_kernel(
    const float* __restrict__ pmu, const float* __restrict__ psig,
    const int* __restrict__ mask2, const float* __restrict__ ws2,
    const float* __restrict__ r2mu, const float* __restrict__ r2sg,
    float* __restrict__ out_mu, float* __restrict__ out_sig)
{
  const int row = blockIdx.x;
  const int tid = threadIdx.x;
  const float rterm = r2mu[row] + r2sg[row];
  const size_t sstride = (size_t)Mrows * N2;
  const float4* mup0 = (const float4*)(pmu + (size_t)row * N2);
  const float4* sbp0 = (const float4*)(psig + (size_t)row * N2);
  const int4* mkp = (const int4*)(mask2 + (size_t)row * N2);
  const float4* wsp = (const float4*)ws2;
  float4* omp = (float4*)(out_mu + (size_t)row * N2);
  float4* osp = (float4*)(out_sig + (size_t)row * N2);
  const size_t s4 = sstride / 4;
  for (int j = tid; j < N2 / 4; j += 256) {
    float4 m4 = mup0[j];
    float4 sb = sbp0[j];
#pragma unroll
    for (int s = 1; s < SPLITK; s++) {
      float4 a = mup0[j + s * s4];
      float4 b = sbp0[j + s * s4];
      m4.x += a.x; m4.y += a.y; m4.z += a.z; m4.w += a.w;
      sb.x += b.x; sb.y += b.y; sb.z += b.z; sb.w += b.w;
    }
    int4 k4 = mkp[j]; float4 w4 = wsp[j];
    float mo[4], so[4];
    float mv[4] = {m4.x, m4.y, m4.z, m4.w};
    float sv[4] = {sb.x, sb.y, sb.z, sb.w};
    float wv[4] = {w4.x, w4.y, w4.z, w4.w};
    int   kv[4] = {k4.x, k4.y, k4.z, k4.w};
#pragma unroll
    for (int t = 0; t < 4; t++) {
      float sig4 = cleanf(sv[t] + rterm * wv[t]);
      float mm = (float)kv[t];
      float mu5 = mv[t] * mm * (1.f / 0.9f);
      float sig5 = cleanf(sig4 * mm * (1.f / 1152.f));
      mo[t] = mu5;
      so[t] = cleanf(sig5);
    }
    omp[j] = make_float4(mo[0], mo[1], mo[2], mo[3]);
    osp[j] = make_float4(so[0], so[1], so[2], so[3]);
  }
}

// ---------------------------------------------------------------------------
extern "C" void kernel_launch(void* const* d_in, const int* in_sizes, int n_in,
                              void* d_out, int out_size, void* d_ws, size_t ws_size,
                              hipStream_t stream)
{
  const float* mu_in = (const float*)d_in[0];
  const float* sg_in = (const float*)d_in[1];
  const int* mask1 = (const int*)d_in[2];
  const int* mask2 = (const int*)d_in[3];
  const float* w_mu1 = (const float*)d_in[4];
  const float* wsig1 = (const float*)d_in[5];
  const float* w_mu2 = (const float*)d_in[6];
  const float* wsig2 = (const float*)d_in[7];
  float* out = (float*)d_out;

  char* ws = (char*)d_ws;
  // Fixed layout with explicit overlays (bytes):
  const size_t oA1  = 0;                           // 37,748,736  A1 / A2
  const size_t oAs  = oA1  + (size_t)37748736;     // As / As2
  const size_t oB1t = oAs  + (size_t)37748736;     // 42,467,328  B1t ; later pmu (75.5MB over B1t+B1q)
  const size_t oB1q = oB1t + (size_t)42467328;     // B1q
  const size_t oB2t = oB1q + (size_t)42467328;     // 10,616,832
  const size_t oB2q = oB2t + (size_t)10616832;
  const size_t oMu1 = oB2q + (size_t)10616832;     // 37,748,736  mu1b ; later psig (75.5MB over mu1b+S1b16)
  const size_t oS1  = oMu1 + (size_t)37748736;     // S1b16
  const size_t oVec = oS1  + (size_t)37748736;

  unsigned short* A1    = (unsigned short*)(ws + oA1);
  unsigned short* As    = (unsigned short*)(ws + oAs);
  unsigned short* B1t   = (unsigned short*)(ws + oB1t);
  unsigned short* B1q   = (unsigned short*)(ws + oB1q);
  unsigned short* B2t   = (unsigned short*)(ws + oB2t);
  unsigned short* B2q   = (unsigned short*)(ws + oB2q);
  unsigned short* mu1b  = (unsigned short*)(ws + oMu1);
  unsigned short* S1b16 = (unsigned short*)(ws + oS1);
  float* pmu  = (float*)(ws + oB1t);   // SPLITK x M x N2 f32 partials (B1t/B1q dead)
  float* psig = (float*)(ws + oMu1);   // SPLITK x M x N2 f32 partials (mu1b/S1b16 dead)

  float* rmu2 = (float*)(ws + oVec);
  float* rsg  = rmu2 + Mrows;
  float* r2mu = rsg + Mrows;
  float* r2sg = r2mu + Mrows;
  float* ws1v = r2sg + Mrows;
  float* ws2v = ws1v + N1;
  float* sumsq = ws2v + N2;

  hipMemsetAsync(sumsq, 0, 2 * sizeof(float), stream);

  prep_in<<<Mrows, 256, 0, stream>>>(mu_in, sg_in, A1, As, rmu2, rsg);
  prep_w<<<dim3(K1 / 32, N1 / 32), 256, 0, stream>>>(w_mu1, B1t, B1q, sumsq, 0, K1, N1);
  prep_w<<<dim3(K1 / 32, N2 / 32), 256, 0, stream>>>(w_mu2, B2t, B2q, sumsq, 1, K1, N2);
  kl_prep<<<1, 256, 0, stream>>>(wsig1, wsig2, sumsq, ws1v, ws2v, out + (size_t)2 * Mrows * N2);

  // layer 1: full-K GEMMs, bf16 out
  gemm_bt<unsigned short><<<dim3(N1 / 128, Mrows / 128, 1), 256, 0, stream>>>(
      A1, B1t, mu1b, Mrows, N1, K1, K1);
  gemm_bt<unsigned short><<<dim3(N1 / 128, Mrows / 128, 1), 256, 0, stream>>>(
      As, B1q, S1b16, Mrows, N1, K1, K1);

  mid_kernel<<<Mrows, 256, 0, stream>>>(mu1b, S1b16, mask1, ws1v, rmu2, rsg, A1, As, r2mu, r2sg);

  // layer 2: split-K=4 GEMMs into f32 partials
  gemm_bt<float><<<dim3(N2 / 128, Mrows / 128, SPLITK), 256, 0, stream>>>(
      A1, B2t, pmu, Mrows, N2, K1, K1 / SPLITK);
  gemm_bt<float><<<dim3(N2 / 128, Mrows / 128, SPLITK), 256, 0, stream>>>(
      As, B2q, psig, Mrows, N2, K1, K1 / SPLITK);

  final_kernel<<<Mrows, 256, 0, stream>>>(pmu, psig, mask2, ws2v, r2mu, r2sg,
                                          out, out + (size_t)Mrows * N2);
  (void)in_sizes; (void)n_in; (void)out_size; (void)ws_size;
}